// Round 4
// baseline (909.165 us; speedup 1.0000x reference)
//
#include <hip/hip_runtime.h>
#include <math.h>

// x: [T=12, B=16, N=2048, D=128] fp32; F = 1536; K = 5
#define TT 12
#define BB 16
#define NN 2048
#define DD 128
#define FDIM 1536
#define KTOP 5
#define NCAND 8
#define NROWS (BB * NN)     // 32768
#define NTRI 136            // 16*17/2 upper-tri 128-tiles per batch

typedef __attribute__((ext_vector_type(8))) short short8;   // 8 bf16
typedef __attribute__((ext_vector_type(4))) float f32x4;
typedef const __attribute__((address_space(1))) void* gas_ptr;
typedef __attribute__((address_space(3))) void* las_ptr;

__device__ __forceinline__ unsigned short f2bf(float f) {   // RNE fp32->bf16
    unsigned u = __float_as_uint(f);
    return (unsigned short)((u + 0x7fffu + ((u >> 16) & 1u)) >> 16);
}
// monotone key: order(key) == order(bf16 value); u32-max-compatible
__device__ __forceinline__ unsigned short bf2key(unsigned short h) {
    return (unsigned short)(h ^ (0x8000u | (0xFFFFu * (h >> 15))));
}

// stable top-k (match lax.top_k: desc value, exact ties -> lowest index)
__device__ __forceinline__ bool tk_better(float v1, int i1, float v2, int i2) {
    return (v1 > v2) || (v1 == v2 && i1 < i2);
}
template <int K>
__device__ __forceinline__ void tk_insert(float bv[K], int bi[K], float v, int idx) {
    if (!tk_better(v, idx, bv[K - 1], bi[K - 1])) return;
    bv[K - 1] = v; bi[K - 1] = idx;
#pragma unroll
    for (int k = K - 1; k > 0; --k) {
        if (tk_better(bv[k], bi[k], bv[k - 1], bi[k - 1])) {
            float tv = bv[k]; bv[k] = bv[k - 1]; bv[k - 1] = tv;
            int tx = bi[k]; bi[k] = bi[k - 1]; bi[k - 1] = tx;
        }
    }
}

// ---------------- 1) fused: row norm + normalized bf16 feature conversion (one wave/row)
__global__ __launch_bounds__(256) void normconv_kernel(const float* __restrict__ x,
                                                       float* __restrict__ invn,
                                                       unsigned short* __restrict__ hi) {
    int lane = threadIdx.x & 63;
    int row  = (blockIdx.x << 2) + (threadIdx.x >> 6);
    int b = row >> 11;
    int n = row & (NN - 1);
    float4 f[6];
    float s = 0.0f;
#pragma unroll
    for (int p = 0; p < 6; ++p) {
        int e = ((p << 6) + lane) << 2;          // float index in [0,1536)
        int t = e >> 7, d = e & 127;
        f[p] = *(const float4*)(x + ((((size_t)t * BB + b) * NN + n) << 7) + d);
        s += f[p].x * f[p].x + f[p].y * f[p].y + f[p].z * f[p].z + f[p].w * f[p].w;
    }
#pragma unroll
    for (int off = 1; off < 64; off <<= 1) s += __shfl_xor(s, off);
    float inv = 1.0f / sqrtf(s);
    if (lane == 0) invn[row] = inv;
    unsigned short* hr = hi + (size_t)row * FDIM;
#pragma unroll
    for (int p = 0; p < 6; ++p) {
        int e = ((p << 6) + lane) << 2;
        ushort4 o;
        o.x = f2bf(f[p].x * inv); o.y = f2bf(f[p].y * inv);
        o.z = f2bf(f[p].z * inv); o.w = f2bf(f[p].w * inv);
        *(ushort4*)(hr + e) = o;
    }
}

// ---------------- 2) bf16 MFMA Gram GEMM: 128x128 tri-tile, K=1536, BK=64
// Output: monotone 16-bit KEYS for cheap u32-max top-k downstream.
__global__ __launch_bounds__(256) void gemm_kernel(const unsigned short* __restrict__ hi,
                                                   unsigned short* __restrict__ dist) {
    __shared__ short As[128 * 64];   // 16 KB
    __shared__ short Bs[128 * 64];   // 16 KB

    int t = blockIdx.x % NTRI;
    int b = blockIdx.x / NTRI;
    int i = 0;
    while (i < 15 && ((i + 1) * (33 - (i + 1))) / 2 <= t) ++i;
    int j = i + (t - (i * (33 - i)) / 2);
    int n0 = i << 7, m0 = j << 7;

    int tid = threadIdx.x;
    int w = tid >> 6, l = tid & 63;

    int offG[4], offL[4];
#pragma unroll
    for (int g = 0; g < 4; ++g) {
        int s = g * 256 + tid;
        int m = s >> 3;
        int c = (s - m) & 7;
        offG[g] = m * FDIM + (c << 3);
        offL[g] = (g << 12) + (w << 10);
    }
    const unsigned short* gA = hi + ((size_t)(b << 11) + n0) * FDIM;
    const unsigned short* gB = hi + ((size_t)(b << 11) + m0) * FDIM;

    int aSlot[4][2], bSlot[4][2];
#pragma unroll
    for (int a = 0; a < 4; ++a)
#pragma unroll
        for (int ki = 0; ki < 2; ++ki) {
            int c  = (ki << 2) + (l >> 4);
            int ma = ((w >> 1) << 6) + (a << 4) + (l & 15);
            int mb = ((w & 1) << 6) + (a << 4) + (l & 15);
            aSlot[a][ki] = (ma << 3) + ((c + ma) & 7);
            bSlot[a][ki] = (mb << 3) + ((c + mb) & 7);
        }

    f32x4 acc[4][4];
#pragma unroll
    for (int a = 0; a < 4; ++a)
#pragma unroll
        for (int c = 0; c < 4; ++c) acc[a][c] = (f32x4){0.f, 0.f, 0.f, 0.f};

    for (int kc = 0; kc < 24; ++kc) {
        int ko = kc << 6;
        __syncthreads();
#pragma unroll
        for (int g = 0; g < 4; ++g) {
            __builtin_amdgcn_global_load_lds((gas_ptr)(gA + ko + offG[g]),
                                             (las_ptr)((char*)As + offL[g]), 16, 0, 0);
            __builtin_amdgcn_global_load_lds((gas_ptr)(gB + ko + offG[g]),
                                             (las_ptr)((char*)Bs + offL[g]), 16, 0, 0);
        }
        __syncthreads();

        short8 af[4][2], bf[4][2];
#pragma unroll
        for (int a = 0; a < 4; ++a)
#pragma unroll
            for (int ki = 0; ki < 2; ++ki) {
                af[a][ki] = *(const short8*)&As[aSlot[a][ki] << 3];
                bf[a][ki] = *(const short8*)&Bs[bSlot[a][ki] << 3];
            }
#pragma unroll
        for (int ki = 0; ki < 2; ++ki)
#pragma unroll
            for (int a = 0; a < 4; ++a)
#pragma unroll
                for (int c = 0; c < 4; ++c)
                    acc[a][c] = __builtin_amdgcn_mfma_f32_16x16x32_bf16(
                        af[a][ki], bf[c][ki], acc[a][c], 0, 0, 0);
    }

    // epilogue: C layout col=lane&15, row=(lane>>4)*4+reg  [m89-verified]
    unsigned short* db = dist + ((size_t)b << 22);
    int rowb = n0 + ((w >> 1) << 6);
    int colb = m0 + ((w & 1) << 6);
#pragma unroll
    for (int a = 0; a < 4; ++a) {
        int r0 = rowb + (a << 4) + ((l >> 4) << 2);
#pragma unroll
        for (int c = 0; c < 4; ++c) {
            int c0 = colb + (c << 4) + (l & 15);
            unsigned short h0 = bf2key(f2bf(acc[a][c][0]));
            unsigned short h1 = bf2key(f2bf(acc[a][c][1]));
            unsigned short h2 = bf2key(f2bf(acc[a][c][2]));
            unsigned short h3 = bf2key(f2bf(acc[a][c][3]));
            db[(size_t)(r0 + 0) * NN + c0] = h0;
            db[(size_t)(r0 + 1) * NN + c0] = h1;
            db[(size_t)(r0 + 2) * NN + c0] = h2;
            db[(size_t)(r0 + 3) * NN + c0] = h3;
            if (i != j) {
                ushort4 o; o.x = h0; o.y = h1; o.z = h2; o.w = h3;
                *(ushort4*)(db + (size_t)c0 * NN + r0) = o;
            }
        }
    }
}

// ---------------- 3) top-8 candidates per row via group-max tournament (one wave/row)
__global__ __launch_bounds__(256) void topk_kernel(const unsigned short* __restrict__ dist,
                                                   int* __restrict__ cand) {
    int wave = threadIdx.x >> 6, lane = threadIdx.x & 63;
    int row  = (blockIdx.x << 2) + wave;
    const unsigned short* p = dist + ((size_t)row << 11);

    unsigned gk[4];
#pragma unroll
    for (int it = 0; it < 4; ++it) {
        int m = (it << 9) + (lane << 3);
        uint4 w2 = *(const uint4*)(p + m);
        unsigned idxv = 2047u - (unsigned)m;
        unsigned best = (w2.x << 16) | idxv;
        unsigned k;
        k = (w2.x & 0xFFFF0000u) | (idxv - 1); best = best > k ? best : k;
        k = (w2.y << 16) | (idxv - 2);         best = best > k ? best : k;
        k = (w2.y & 0xFFFF0000u) | (idxv - 3); best = best > k ? best : k;
        k = (w2.z << 16) | (idxv - 4);         best = best > k ? best : k;
        k = (w2.z & 0xFFFF0000u) | (idxv - 5); best = best > k ? best : k;
        k = (w2.w << 16) | (idxv - 6);         best = best > k ? best : k;
        k = (w2.w & 0xFFFF0000u) | (idxv - 7); best = best > k ? best : k;
        gk[it] = best;
    }

    unsigned mywg = 0;
#pragma unroll
    for (int pass = 0; pass < 8; ++pass) {
        unsigned mx0 = gk[0] > gk[1] ? gk[0] : gk[1];
        unsigned mx1 = gk[2] > gk[3] ? gk[2] : gk[3];
        unsigned mx = mx0 > mx1 ? mx0 : mx1;
#pragma unroll
        for (int off = 1; off < 64; off <<= 1) {
            unsigned o = (unsigned)__shfl_xor((int)mx, off);
            mx = mx > o ? mx : o;
        }
        if (lane == pass) mywg = mx;
#pragma unroll
        for (int tt = 0; tt < 4; ++tt)
            if (gk[tt] == mx) gk[tt] = 0;
    }

    unsigned gkey = (unsigned)__shfl((int)mywg, lane >> 3);
    int gm = 2047 - (int)(gkey & 0x7FFu);
    int m  = ((gm >> 3) << 3) + (lane & 7);
    unsigned key = ((unsigned)p[m] << 16) | (unsigned)(2047 - m);
    int mycand = 0;
#pragma unroll
    for (int pass = 0; pass < 8; ++pass) {
        unsigned mx = key;
#pragma unroll
        for (int off = 1; off < 64; off <<= 1) {
            unsigned o = (unsigned)__shfl_xor((int)mx, off);
            mx = mx > o ? mx : o;
        }
        if (lane == pass) mycand = 2047 - (int)(mx & 0x7FFu);
        if (key == mx) key = 0;
    }
    if (lane < 8) cand[row * NCAND + lane] = mycand;
}

// ---------------- 4) exact fp32 rescore (MLP-restructured) + fused scatter
// One wave per row. All 48 candidate loads independent of any reduction;
// 8 butterfly reduce chains interleave at the end. d_out is already zeroed.
__global__ __launch_bounds__(256, 4) void rescore_kernel(const float* __restrict__ x,
                                                         const float* __restrict__ invn,
                                                         const int* __restrict__ cand,
                                                         float* __restrict__ out) {
    int wave = threadIdx.x >> 6, l = threadIdx.x & 63;
    int row  = (blockIdx.x << 2) + wave;
    int b = row >> 11, n = row & (NN - 1);

    int4 c0 = *(const int4*)(cand + row * NCAND);
    int4 c1 = *(const int4*)(cand + row * NCAND + 4);
    int cix[NCAND] = {c0.x, c0.y, c0.z, c0.w, c1.x, c1.y, c1.z, c1.w};

    // own row fragment (6 float4 per lane)
    float4 fn[6];
#pragma unroll
    for (int p = 0; p < 6; ++p) {
        int e = ((p << 6) + l) << 2;
        int t = e >> 7, d = e & 127;
        fn[p] = *(const float4*)(x + ((((size_t)t * BB + b) * NN + n) << 7) + d);
    }

    // 8 independent partial dots — no cross-lane dependency yet
    float acc[NCAND];
#pragma unroll
    for (int c = 0; c < NCAND; ++c) acc[c] = 0.0f;
#pragma unroll
    for (int c = 0; c < NCAND; ++c) {
        int m = cix[c];
#pragma unroll
        for (int p = 0; p < 6; ++p) {
            int e = ((p << 6) + l) << 2;
            int t = e >> 7, d = e & 127;
            float4 v = *(const float4*)(x + ((((size_t)t * BB + b) * NN + m) << 7) + d);
            acc[c] += fn[p].x * v.x + fn[p].y * v.y + fn[p].z * v.z + fn[p].w * v.w;
        }
    }

    // 8 interleaved butterfly reductions (all lanes end with full sums)
#pragma unroll
    for (int off = 1; off < 64; off <<= 1) {
#pragma unroll
        for (int c = 0; c < NCAND; ++c) acc[c] += __shfl_xor(acc[c], off);
    }

    if (l == 0) {
        float sn = invn[row];
        float bv[KTOP]; int bi[KTOP];
#pragma unroll
        for (int k = 0; k < KTOP; ++k) { bv[k] = -3.0e38f; bi[k] = 1 << 30; }
#pragma unroll
        for (int c = 0; c < NCAND; ++c) {
            float v = acc[c] * sn * invn[(b << 11) + cix[c]];
            tk_insert<KTOP>(bv, bi, v, cix[c]);
        }
        // fused scatter: out += leaky(v)*0.5 at (n,m) and (m,n)
        float* base = out + ((size_t)b << 22);
#pragma unroll
        for (int k = 0; k < KTOP; ++k) {
            float v = bv[k];
            int m = bi[k];
            float a = (v >= 0.0f ? v : 0.01f * v) * 0.5f;
            atomicAdd(base + ((size_t)n << 11) + m, a);
            atomicAdd(base + ((size_t)m << 11) + n, a);
        }
    }
}

extern "C" void kernel_launch(void* const* d_in, const int* in_sizes, int n_in,
                              void* d_out, int out_size, void* d_ws, size_t ws_size,
                              hipStream_t stream) {
    const float* x = (const float*)d_in[0];
    float* out = (float*)d_out;

    // d_out doubles as scratch until the memset:
    //   [0, 134MB)   16-bit monotone dist keys [16][2048][2048]  (last read: topk)
    //   [134, 235MB) bf16 normalized features hi [16][2048][1536] (last read: gemm)
    unsigned short* dist = (unsigned short*)d_out;
    unsigned short* hi   = (unsigned short*)((char*)d_out + 134217728);

    // ws: invn 128KB | cand 1MB
    float* invn = (float*)d_ws;
    int*   cand = (int*)(invn + NROWS);

    normconv_kernel<<<NROWS / 4, 256, 0, stream>>>(x, invn, hi);
    gemm_kernel<<<NTRI * BB, 256, 0, stream>>>(hi, dist);
    topk_kernel<<<NROWS / 4, 256, 0, stream>>>(dist, cand);
    hipMemsetAsync(d_out, 0, (size_t)out_size * sizeof(float), stream);
    rescore_kernel<<<NROWS / 4, 256, 0, stream>>>(x, invn, cand, out);
}

// Round 5
// 793.673 us; speedup vs baseline: 1.1455x; 1.1455x over previous
//
#include <hip/hip_runtime.h>
#include <math.h>

// x: [T=12, B=16, N=2048, D=128] fp32; F = 1536; K = 5
#define TT 12
#define BB 16
#define NN 2048
#define DD 128
#define FDIM 1536
#define KTOP 5
#define NCAND 8
#define NROWS (BB * NN)     // 32768
#define NTRI 136            // 16*17/2 upper-tri 128-tiles per batch

typedef __attribute__((ext_vector_type(8))) short short8;   // 8 bf16
typedef __attribute__((ext_vector_type(4))) float f32x4;
typedef const __attribute__((address_space(1))) void* gas_ptr;
typedef __attribute__((address_space(3))) void* las_ptr;

__device__ __forceinline__ unsigned short f2bf(float f) {   // RNE fp32->bf16
    unsigned u = __float_as_uint(f);
    return (unsigned short)((u + 0x7fffu + ((u >> 16) & 1u)) >> 16);
}
// monotone key: order(key) == order(bf16 value); u32-max-compatible
__device__ __forceinline__ unsigned short bf2key(unsigned short h) {
    return (unsigned short)(h ^ (0x8000u | (0xFFFFu * (h >> 15))));
}

// stable top-k (match lax.top_k: desc value, exact ties -> lowest index)
__device__ __forceinline__ bool tk_better(float v1, int i1, float v2, int i2) {
    return (v1 > v2) || (v1 == v2 && i1 < i2);
}
template <int K>
__device__ __forceinline__ void tk_insert(float bv[K], int bi[K], float v, int idx) {
    if (!tk_better(v, idx, bv[K - 1], bi[K - 1])) return;
    bv[K - 1] = v; bi[K - 1] = idx;
#pragma unroll
    for (int k = K - 1; k > 0; --k) {
        if (tk_better(bv[k], bi[k], bv[k - 1], bi[k - 1])) {
            float tv = bv[k]; bv[k] = bv[k - 1]; bv[k - 1] = tv;
            int tx = bi[k]; bi[k] = bi[k - 1]; bi[k - 1] = tx;
        }
    }
}

// ---------------- 1) fused: row norm + normalized bf16 feature conversion (one wave/row)
__global__ __launch_bounds__(256) void normconv_kernel(const float* __restrict__ x,
                                                       float* __restrict__ invn,
                                                       unsigned short* __restrict__ hi) {
    int lane = threadIdx.x & 63;
    int row  = (blockIdx.x << 2) + (threadIdx.x >> 6);
    int b = row >> 11;
    int n = row & (NN - 1);
    float4 f[6];
    float s = 0.0f;
#pragma unroll
    for (int p = 0; p < 6; ++p) {
        int e = ((p << 6) + lane) << 2;          // float index in [0,1536)
        int t = e >> 7, d = e & 127;
        f[p] = *(const float4*)(x + ((((size_t)t * BB + b) * NN + n) << 7) + d);
        s += f[p].x * f[p].x + f[p].y * f[p].y + f[p].z * f[p].z + f[p].w * f[p].w;
    }
#pragma unroll
    for (int off = 1; off < 64; off <<= 1) s += __shfl_xor(s, off);
    float inv = 1.0f / sqrtf(s);
    if (lane == 0) invn[row] = inv;
    unsigned short* hr = hi + (size_t)row * FDIM;
#pragma unroll
    for (int p = 0; p < 6; ++p) {
        int e = ((p << 6) + lane) << 2;
        ushort4 o;
        o.x = f2bf(f[p].x * inv); o.y = f2bf(f[p].y * inv);
        o.z = f2bf(f[p].z * inv); o.w = f2bf(f[p].w * inv);
        *(ushort4*)(hr + e) = o;
    }
}

// ---------------- 2) bf16 MFMA Gram GEMM: 128x128 tri-tile, K=1536, BK=64
// Output: monotone 16-bit KEYS for cheap u32-max top-k downstream.
__global__ __launch_bounds__(256) void gemm_kernel(const unsigned short* __restrict__ hi,
                                                   unsigned short* __restrict__ dist) {
    __shared__ short As[128 * 64];   // 16 KB
    __shared__ short Bs[128 * 64];   // 16 KB

    int t = blockIdx.x % NTRI;
    int b = blockIdx.x / NTRI;
    int i = 0;
    while (i < 15 && ((i + 1) * (33 - (i + 1))) / 2 <= t) ++i;
    int j = i + (t - (i * (33 - i)) / 2);
    int n0 = i << 7, m0 = j << 7;

    int tid = threadIdx.x;
    int w = tid >> 6, l = tid & 63;

    int offG[4], offL[4];
#pragma unroll
    for (int g = 0; g < 4; ++g) {
        int s = g * 256 + tid;
        int m = s >> 3;
        int c = (s - m) & 7;
        offG[g] = m * FDIM + (c << 3);
        offL[g] = (g << 12) + (w << 10);
    }
    const unsigned short* gA = hi + ((size_t)(b << 11) + n0) * FDIM;
    const unsigned short* gB = hi + ((size_t)(b << 11) + m0) * FDIM;

    int aSlot[4][2], bSlot[4][2];
#pragma unroll
    for (int a = 0; a < 4; ++a)
#pragma unroll
        for (int ki = 0; ki < 2; ++ki) {
            int c  = (ki << 2) + (l >> 4);
            int ma = ((w >> 1) << 6) + (a << 4) + (l & 15);
            int mb = ((w & 1) << 6) + (a << 4) + (l & 15);
            aSlot[a][ki] = (ma << 3) + ((c + ma) & 7);
            bSlot[a][ki] = (mb << 3) + ((c + mb) & 7);
        }

    f32x4 acc[4][4];
#pragma unroll
    for (int a = 0; a < 4; ++a)
#pragma unroll
        for (int c = 0; c < 4; ++c) acc[a][c] = (f32x4){0.f, 0.f, 0.f, 0.f};

    for (int kc = 0; kc < 24; ++kc) {
        int ko = kc << 6;
        __syncthreads();
#pragma unroll
        for (int g = 0; g < 4; ++g) {
            __builtin_amdgcn_global_load_lds((gas_ptr)(gA + ko + offG[g]),
                                             (las_ptr)((char*)As + offL[g]), 16, 0, 0);
            __builtin_amdgcn_global_load_lds((gas_ptr)(gB + ko + offG[g]),
                                             (las_ptr)((char*)Bs + offL[g]), 16, 0, 0);
        }
        __syncthreads();

        short8 af[4][2], bf[4][2];
#pragma unroll
        for (int a = 0; a < 4; ++a)
#pragma unroll
            for (int ki = 0; ki < 2; ++ki) {
                af[a][ki] = *(const short8*)&As[aSlot[a][ki] << 3];
                bf[a][ki] = *(const short8*)&Bs[bSlot[a][ki] << 3];
            }
#pragma unroll
        for (int ki = 0; ki < 2; ++ki)
#pragma unroll
            for (int a = 0; a < 4; ++a)
#pragma unroll
                for (int c = 0; c < 4; ++c)
                    acc[a][c] = __builtin_amdgcn_mfma_f32_16x16x32_bf16(
                        af[a][ki], bf[c][ki], acc[a][c], 0, 0, 0);
    }

    // epilogue: C layout col=lane&15, row=(lane>>4)*4+reg  [m89-verified]
    unsigned short* db = dist + ((size_t)b << 22);
    int rowb = n0 + ((w >> 1) << 6);
    int colb = m0 + ((w & 1) << 6);
#pragma unroll
    for (int a = 0; a < 4; ++a) {
        int r0 = rowb + (a << 4) + ((l >> 4) << 2);
#pragma unroll
        for (int c = 0; c < 4; ++c) {
            int c0 = colb + (c << 4) + (l & 15);
            unsigned short h0 = bf2key(f2bf(acc[a][c][0]));
            unsigned short h1 = bf2key(f2bf(acc[a][c][1]));
            unsigned short h2 = bf2key(f2bf(acc[a][c][2]));
            unsigned short h3 = bf2key(f2bf(acc[a][c][3]));
            db[(size_t)(r0 + 0) * NN + c0] = h0;
            db[(size_t)(r0 + 1) * NN + c0] = h1;
            db[(size_t)(r0 + 2) * NN + c0] = h2;
            db[(size_t)(r0 + 3) * NN + c0] = h3;
            if (i != j) {
                ushort4 o; o.x = h0; o.y = h1; o.z = h2; o.w = h3;
                *(ushort4*)(db + (size_t)c0 * NN + r0) = o;
            }
        }
    }
}

// ---------------- 3) top-8 candidates per row via group-max tournament (one wave/row)
__global__ __launch_bounds__(256) void topk_kernel(const unsigned short* __restrict__ dist,
                                                   int* __restrict__ cand) {
    int wave = threadIdx.x >> 6, lane = threadIdx.x & 63;
    int row  = (blockIdx.x << 2) + wave;
    const unsigned short* p = dist + ((size_t)row << 11);

    unsigned gk[4];
#pragma unroll
    for (int it = 0; it < 4; ++it) {
        int m = (it << 9) + (lane << 3);
        uint4 w2 = *(const uint4*)(p + m);
        unsigned idxv = 2047u - (unsigned)m;
        unsigned best = (w2.x << 16) | idxv;
        unsigned k;
        k = (w2.x & 0xFFFF0000u) | (idxv - 1); best = best > k ? best : k;
        k = (w2.y << 16) | (idxv - 2);         best = best > k ? best : k;
        k = (w2.y & 0xFFFF0000u) | (idxv - 3); best = best > k ? best : k;
        k = (w2.z << 16) | (idxv - 4);         best = best > k ? best : k;
        k = (w2.z & 0xFFFF0000u) | (idxv - 5); best = best > k ? best : k;
        k = (w2.w << 16) | (idxv - 6);         best = best > k ? best : k;
        k = (w2.w & 0xFFFF0000u) | (idxv - 7); best = best > k ? best : k;
        gk[it] = best;
    }

    unsigned mywg = 0;
#pragma unroll
    for (int pass = 0; pass < 8; ++pass) {
        unsigned mx0 = gk[0] > gk[1] ? gk[0] : gk[1];
        unsigned mx1 = gk[2] > gk[3] ? gk[2] : gk[3];
        unsigned mx = mx0 > mx1 ? mx0 : mx1;
#pragma unroll
        for (int off = 1; off < 64; off <<= 1) {
            unsigned o = (unsigned)__shfl_xor((int)mx, off);
            mx = mx > o ? mx : o;
        }
        if (lane == pass) mywg = mx;
#pragma unroll
        for (int tt = 0; tt < 4; ++tt)
            if (gk[tt] == mx) gk[tt] = 0;
    }

    unsigned gkey = (unsigned)__shfl((int)mywg, lane >> 3);
    int gm = 2047 - (int)(gkey & 0x7FFu);
    int m  = ((gm >> 3) << 3) + (lane & 7);
    unsigned key = ((unsigned)p[m] << 16) | (unsigned)(2047 - m);
    int mycand = 0;
#pragma unroll
    for (int pass = 0; pass < 8; ++pass) {
        unsigned mx = key;
#pragma unroll
        for (int off = 1; off < 64; off <<= 1) {
            unsigned o = (unsigned)__shfl_xor((int)mx, off);
            mx = mx > o ? mx : o;
        }
        if (lane == pass) mycand = 2047 - (int)(mx & 0x7FFu);
        if (key == mx) key = 0;
    }
    if (lane < 8) cand[row * NCAND + lane] = mycand;
}

// ---------------- 4) exact fp32 rescore, PHASE-OUTER (9 independent loads/phase) + fused scatter
// One wave per row. Each phase: 1 own-row float4 + 8 candidate float4 loads, all
// independent, consumed immediately -> 8-way MLP with short live ranges (no spill bait).
__global__ __launch_bounds__(256, 4) void rescore_kernel(const float* __restrict__ x,
                                                         const float* __restrict__ invn,
                                                         const int* __restrict__ cand,
                                                         float* __restrict__ out) {
    int wave = threadIdx.x >> 6, l = threadIdx.x & 63;
    int row  = (blockIdx.x << 2) + wave;
    int b = row >> 11, n = row & (NN - 1);

    int4 c0 = *(const int4*)(cand + row * NCAND);
    int4 c1 = *(const int4*)(cand + row * NCAND + 4);
    int cix[NCAND] = {c0.x, c0.y, c0.z, c0.w, c1.x, c1.y, c1.z, c1.w};

    float acc[NCAND];
#pragma unroll
    for (int c = 0; c < NCAND; ++c) acc[c] = 0.0f;

#pragma unroll 2
    for (int p = 0; p < 6; ++p) {
        int e = ((p << 6) + l) << 2;           // float index in [0,1536)
        int t = e >> 7, d = e & 127;
        const float* base = x + ((((size_t)t * BB + b) * NN) << 7) + d;
        float4 fn = *(const float4*)(base + ((size_t)n << 7));
        float4 v[NCAND];
#pragma unroll
        for (int c = 0; c < NCAND; ++c)
            v[c] = *(const float4*)(base + ((size_t)cix[c] << 7));
#pragma unroll
        for (int c = 0; c < NCAND; ++c)
            acc[c] += fn.x * v[c].x + fn.y * v[c].y + fn.z * v[c].z + fn.w * v[c].w;
    }

    // 8 interleaved butterfly reductions
#pragma unroll
    for (int off = 1; off < 64; off <<= 1) {
#pragma unroll
        for (int c = 0; c < NCAND; ++c) acc[c] += __shfl_xor(acc[c], off);
    }

    if (l == 0) {
        float sn = invn[row];
        float bv[KTOP]; int bi[KTOP];
#pragma unroll
        for (int k = 0; k < KTOP; ++k) { bv[k] = -3.0e38f; bi[k] = 1 << 30; }
#pragma unroll
        for (int c = 0; c < NCAND; ++c) {
            float v = acc[c] * sn * invn[(b << 11) + cix[c]];
            tk_insert<KTOP>(bv, bi, v, cix[c]);
        }
        // fused scatter: out += leaky(v)*0.5 at (n,m) and (m,n); out pre-zeroed
        float* base = out + ((size_t)b << 22);
#pragma unroll
        for (int k = 0; k < KTOP; ++k) {
            float v = bv[k];
            int m = bi[k];
            float a = (v >= 0.0f ? v : 0.01f * v) * 0.5f;
            atomicAdd(base + ((size_t)n << 11) + m, a);
            atomicAdd(base + ((size_t)m << 11) + n, a);
        }
    }
}

extern "C" void kernel_launch(void* const* d_in, const int* in_sizes, int n_in,
                              void* d_out, int out_size, void* d_ws, size_t ws_size,
                              hipStream_t stream) {
    const float* x = (const float*)d_in[0];
    float* out = (float*)d_out;

    // d_out doubles as scratch until the memset:
    //   [0, 134MB)   16-bit monotone dist keys [16][2048][2048]  (last read: topk)
    //   [134, 235MB) bf16 normalized features hi [16][2048][1536] (last read: gemm)
    unsigned short* dist = (unsigned short*)d_out;
    unsigned short* hi   = (unsigned short*)((char*)d_out + 134217728);

    // ws: invn 128KB | cand 1MB
    float* invn = (float*)d_ws;
    int*   cand = (int*)(invn + NROWS);

    normconv_kernel<<<NROWS / 4, 256, 0, stream>>>(x, invn, hi);
    gemm_kernel<<<NTRI * BB, 256, 0, stream>>>(hi, dist);
    topk_kernel<<<NROWS / 4, 256, 0, stream>>>(dist, cand);
    hipMemsetAsync(d_out, 0, (size_t)out_size * sizeof(float), stream);
    rescore_kernel<<<NROWS / 4, 256, 0, stream>>>(x, invn, cand, out);
}

// Round 6
// 781.185 us; speedup vs baseline: 1.1638x; 1.0160x over previous
//
#include <hip/hip_runtime.h>
#include <math.h>

// x: [T=12, B=16, N=2048, D=128] fp32; F = 1536; K = 5
#define TT 12
#define BB 16
#define NN 2048
#define DD 128
#define FDIM 1536
#define KTOP 5
#define NCAND 8
#define NROWS (BB * NN)     // 32768
#define NTRI 136            // 16*17/2 upper-tri 128-tiles per batch
#define OUTSZ (BB * NN * NN)

typedef __attribute__((ext_vector_type(8))) short short8;   // 8 bf16
typedef __attribute__((ext_vector_type(4))) float f32x4;
typedef const __attribute__((address_space(1))) void* gas_ptr;
typedef __attribute__((address_space(3))) void* las_ptr;

__device__ __forceinline__ unsigned short f2bf(float f) {   // RNE fp32->bf16
    unsigned u = __float_as_uint(f);
    return (unsigned short)((u + 0x7fffu + ((u >> 16) & 1u)) >> 16);
}
// monotone key: order(key) == order(bf16 value); u32-max-compatible
__device__ __forceinline__ unsigned short bf2key(unsigned short h) {
    return (unsigned short)(h ^ (0x8000u | (0xFFFFu * (h >> 15))));
}

// stable top-k (match lax.top_k: desc value, exact ties -> lowest index)
__device__ __forceinline__ bool tk_better(float v1, int i1, float v2, int i2) {
    return (v1 > v2) || (v1 == v2 && i1 < i2);
}
template <int K>
__device__ __forceinline__ void tk_insert(float bv[K], int bi[K], float v, int idx) {
    if (!tk_better(v, idx, bv[K - 1], bi[K - 1])) return;
    bv[K - 1] = v; bi[K - 1] = idx;
#pragma unroll
    for (int k = K - 1; k > 0; --k) {
        if (tk_better(bv[k], bi[k], bv[k - 1], bi[k - 1])) {
            float tv = bv[k]; bv[k] = bv[k - 1]; bv[k - 1] = tv;
            int tx = bi[k]; bi[k] = bi[k - 1]; bi[k - 1] = tx;
        }
    }
}

// ---------------- 0) grid-stride zero kernel (replaces hipMemsetAsync; controlled BW)
__global__ __launch_bounds__(256) void zero_kernel(float4* __restrict__ out) {
    // 16777216 float4s total; 8192 blocks * 256 threads * 8 float4s
    size_t base = (size_t)blockIdx.x * 2048 + threadIdx.x;
    float4 z = make_float4(0.f, 0.f, 0.f, 0.f);
#pragma unroll
    for (int k = 0; k < 8; ++k) out[base + (size_t)k * 256] = z;
}

// ---------------- 1) fused: row norm + normalized bf16 feature conversion (one wave/row)
__global__ __launch_bounds__(256) void normconv_kernel(const float* __restrict__ x,
                                                       float* __restrict__ invn,
                                                       unsigned short* __restrict__ hi) {
    int lane = threadIdx.x & 63;
    int row  = (blockIdx.x << 2) + (threadIdx.x >> 6);
    int b = row >> 11;
    int n = row & (NN - 1);
    float4 f[6];
    float s = 0.0f;
#pragma unroll
    for (int p = 0; p < 6; ++p) {
        int e = ((p << 6) + lane) << 2;          // float index in [0,1536)
        int t = e >> 7, d = e & 127;
        f[p] = *(const float4*)(x + ((((size_t)t * BB + b) * NN + n) << 7) + d);
        s += f[p].x * f[p].x + f[p].y * f[p].y + f[p].z * f[p].z + f[p].w * f[p].w;
    }
#pragma unroll
    for (int off = 1; off < 64; off <<= 1) s += __shfl_xor(s, off);
    float inv = 1.0f / sqrtf(s);
    if (lane == 0) invn[row] = inv;
    unsigned short* hr = hi + (size_t)row * FDIM;
#pragma unroll
    for (int p = 0; p < 6; ++p) {
        int e = ((p << 6) + lane) << 2;
        ushort4 o;
        o.x = f2bf(f[p].x * inv); o.y = f2bf(f[p].y * inv);
        o.z = f2bf(f[p].z * inv); o.w = f2bf(f[p].w * inv);
        *(ushort4*)(hr + e) = o;
    }
}

// ---------------- 2) bf16 MFMA Gram GEMM: 128x128 tri-tile, K=1536, BK=64
// Output: monotone 16-bit KEYS for cheap u32-max top-k downstream.
// launch_bounds(256,3): arch 96 + acc 64 = 160 VGPR <= 512/3 -> 3 waves/SIMD resident.
__global__ __launch_bounds__(256, 3) void gemm_kernel(const unsigned short* __restrict__ hi,
                                                      unsigned short* __restrict__ dist) {
    __shared__ short As[128 * 64];   // 16 KB
    __shared__ short Bs[128 * 64];   // 16 KB

    int t = blockIdx.x % NTRI;
    int b = blockIdx.x / NTRI;
    int i = 0;
    while (i < 15 && ((i + 1) * (33 - (i + 1))) / 2 <= t) ++i;
    int j = i + (t - (i * (33 - i)) / 2);
    int n0 = i << 7, m0 = j << 7;

    int tid = threadIdx.x;
    int w = tid >> 6, l = tid & 63;

    int offG[4], offL[4];
#pragma unroll
    for (int g = 0; g < 4; ++g) {
        int s = g * 256 + tid;
        int m = s >> 3;
        int c = (s - m) & 7;
        offG[g] = m * FDIM + (c << 3);
        offL[g] = (g << 12) + (w << 10);
    }
    const unsigned short* gA = hi + ((size_t)(b << 11) + n0) * FDIM;
    const unsigned short* gB = hi + ((size_t)(b << 11) + m0) * FDIM;

    int aSlot[4][2], bSlot[4][2];
#pragma unroll
    for (int a = 0; a < 4; ++a)
#pragma unroll
        for (int ki = 0; ki < 2; ++ki) {
            int c  = (ki << 2) + (l >> 4);
            int ma = ((w >> 1) << 6) + (a << 4) + (l & 15);
            int mb = ((w & 1) << 6) + (a << 4) + (l & 15);
            aSlot[a][ki] = (ma << 3) + ((c + ma) & 7);
            bSlot[a][ki] = (mb << 3) + ((c + mb) & 7);
        }

    f32x4 acc[4][4];
#pragma unroll
    for (int a = 0; a < 4; ++a)
#pragma unroll
        for (int c = 0; c < 4; ++c) acc[a][c] = (f32x4){0.f, 0.f, 0.f, 0.f};

    for (int kc = 0; kc < 24; ++kc) {
        int ko = kc << 6;
        __syncthreads();
#pragma unroll
        for (int g = 0; g < 4; ++g) {
            __builtin_amdgcn_global_load_lds((gas_ptr)(gA + ko + offG[g]),
                                             (las_ptr)((char*)As + offL[g]), 16, 0, 0);
            __builtin_amdgcn_global_load_lds((gas_ptr)(gB + ko + offG[g]),
                                             (las_ptr)((char*)Bs + offL[g]), 16, 0, 0);
        }
        __syncthreads();

        short8 af[4][2], bf[4][2];
#pragma unroll
        for (int a = 0; a < 4; ++a)
#pragma unroll
            for (int ki = 0; ki < 2; ++ki) {
                af[a][ki] = *(const short8*)&As[aSlot[a][ki] << 3];
                bf[a][ki] = *(const short8*)&Bs[bSlot[a][ki] << 3];
            }
#pragma unroll
        for (int ki = 0; ki < 2; ++ki)
#pragma unroll
            for (int a = 0; a < 4; ++a)
#pragma unroll
                for (int c = 0; c < 4; ++c)
                    acc[a][c] = __builtin_amdgcn_mfma_f32_16x16x32_bf16(
                        af[a][ki], bf[c][ki], acc[a][c], 0, 0, 0);
    }

    // epilogue: C layout col=lane&15, row=(lane>>4)*4+reg  [m89-verified]
    unsigned short* db = dist + ((size_t)b << 22);
    int rowb = n0 + ((w >> 1) << 6);
    int colb = m0 + ((w & 1) << 6);
#pragma unroll
    for (int a = 0; a < 4; ++a) {
        int r0 = rowb + (a << 4) + ((l >> 4) << 2);
#pragma unroll
        for (int c = 0; c < 4; ++c) {
            int c0 = colb + (c << 4) + (l & 15);
            unsigned short h0 = bf2key(f2bf(acc[a][c][0]));
            unsigned short h1 = bf2key(f2bf(acc[a][c][1]));
            unsigned short h2 = bf2key(f2bf(acc[a][c][2]));
            unsigned short h3 = bf2key(f2bf(acc[a][c][3]));
            db[(size_t)(r0 + 0) * NN + c0] = h0;
            db[(size_t)(r0 + 1) * NN + c0] = h1;
            db[(size_t)(r0 + 2) * NN + c0] = h2;
            db[(size_t)(r0 + 3) * NN + c0] = h3;
            if (i != j) {
                ushort4 o; o.x = h0; o.y = h1; o.z = h2; o.w = h3;
                *(ushort4*)(db + (size_t)c0 * NN + r0) = o;
            }
        }
    }
}

// ---------------- 3) top-8 candidates per row via group-max tournament (one wave/row)
__global__ __launch_bounds__(256) void topk_kernel(const unsigned short* __restrict__ dist,
                                                   int* __restrict__ cand) {
    int wave = threadIdx.x >> 6, lane = threadIdx.x & 63;
    int row  = (blockIdx.x << 2) + wave;
    const unsigned short* p = dist + ((size_t)row << 11);

    unsigned gk[4];
#pragma unroll
    for (int it = 0; it < 4; ++it) {
        int m = (it << 9) + (lane << 3);
        uint4 w2 = *(const uint4*)(p + m);
        unsigned idxv = 2047u - (unsigned)m;
        unsigned best = (w2.x << 16) | idxv;
        unsigned k;
        k = (w2.x & 0xFFFF0000u) | (idxv - 1); best = best > k ? best : k;
        k = (w2.y << 16) | (idxv - 2);         best = best > k ? best : k;
        k = (w2.y & 0xFFFF0000u) | (idxv - 3); best = best > k ? best : k;
        k = (w2.z << 16) | (idxv - 4);         best = best > k ? best : k;
        k = (w2.z & 0xFFFF0000u) | (idxv - 5); best = best > k ? best : k;
        k = (w2.w << 16) | (idxv - 6);         best = best > k ? best : k;
        k = (w2.w & 0xFFFF0000u) | (idxv - 7); best = best > k ? best : k;
        gk[it] = best;
    }

    unsigned mywg = 0;
#pragma unroll
    for (int pass = 0; pass < 8; ++pass) {
        unsigned mx0 = gk[0] > gk[1] ? gk[0] : gk[1];
        unsigned mx1 = gk[2] > gk[3] ? gk[2] : gk[3];
        unsigned mx = mx0 > mx1 ? mx0 : mx1;
#pragma unroll
        for (int off = 1; off < 64; off <<= 1) {
            unsigned o = (unsigned)__shfl_xor((int)mx, off);
            mx = mx > o ? mx : o;
        }
        if (lane == pass) mywg = mx;
#pragma unroll
        for (int tt = 0; tt < 4; ++tt)
            if (gk[tt] == mx) gk[tt] = 0;
    }

    unsigned gkey = (unsigned)__shfl((int)mywg, lane >> 3);
    int gm = 2047 - (int)(gkey & 0x7FFu);
    int m  = ((gm >> 3) << 3) + (lane & 7);
    unsigned key = ((unsigned)p[m] << 16) | (unsigned)(2047 - m);
    int mycand = 0;
#pragma unroll
    for (int pass = 0; pass < 8; ++pass) {
        unsigned mx = key;
#pragma unroll
        for (int off = 1; off < 64; off <<= 1) {
            unsigned o = (unsigned)__shfl_xor((int)mx, off);
            mx = mx > o ? mx : o;
        }
        if (lane == pass) mycand = 2047 - (int)(mx & 0x7FFu);
        if (key == mx) key = 0;
    }
    if (lane < 8) cand[row * NCAND + lane] = mycand;
}

// ---------------- 4) exact fp32 rescore, PHASE-OUTER (9 independent loads/phase) + fused scatter
__global__ __launch_bounds__(256, 4) void rescore_kernel(const float* __restrict__ x,
                                                         const float* __restrict__ invn,
                                                         const int* __restrict__ cand,
                                                         float* __restrict__ out) {
    int wave = threadIdx.x >> 6, l = threadIdx.x & 63;
    int row  = (blockIdx.x << 2) + wave;
    int b = row >> 11, n = row & (NN - 1);

    int4 c0 = *(const int4*)(cand + row * NCAND);
    int4 c1 = *(const int4*)(cand + row * NCAND + 4);
    int cix[NCAND] = {c0.x, c0.y, c0.z, c0.w, c1.x, c1.y, c1.z, c1.w};

    float acc[NCAND];
#pragma unroll
    for (int c = 0; c < NCAND; ++c) acc[c] = 0.0f;

#pragma unroll 2
    for (int p = 0; p < 6; ++p) {
        int e = ((p << 6) + l) << 2;           // float index in [0,1536)
        int t = e >> 7, d = e & 127;
        const float* base = x + ((((size_t)t * BB + b) * NN) << 7) + d;
        float4 fn = *(const float4*)(base + ((size_t)n << 7));
        float4 v[NCAND];
#pragma unroll
        for (int c = 0; c < NCAND; ++c)
            v[c] = *(const float4*)(base + ((size_t)cix[c] << 7));
#pragma unroll
        for (int c = 0; c < NCAND; ++c)
            acc[c] += fn.x * v[c].x + fn.y * v[c].y + fn.z * v[c].z + fn.w * v[c].w;
    }

#pragma unroll
    for (int off = 1; off < 64; off <<= 1) {
#pragma unroll
        for (int c = 0; c < NCAND; ++c) acc[c] += __shfl_xor(acc[c], off);
    }

    if (l == 0) {
        float sn = invn[row];
        float bv[KTOP]; int bi[KTOP];
#pragma unroll
        for (int k = 0; k < KTOP; ++k) { bv[k] = -3.0e38f; bi[k] = 1 << 30; }
#pragma unroll
        for (int c = 0; c < NCAND; ++c) {
            float v = acc[c] * sn * invn[(b << 11) + cix[c]];
            tk_insert<KTOP>(bv, bi, v, cix[c]);
        }
        float* base = out + ((size_t)b << 22);
#pragma unroll
        for (int k = 0; k < KTOP; ++k) {
            float v = bv[k];
            int m = bi[k];
            float a = (v >= 0.0f ? v : 0.01f * v) * 0.5f;
            atomicAdd(base + ((size_t)n << 11) + m, a);
            atomicAdd(base + ((size_t)m << 11) + n, a);
        }
    }
}

extern "C" void kernel_launch(void* const* d_in, const int* in_sizes, int n_in,
                              void* d_out, int out_size, void* d_ws, size_t ws_size,
                              hipStream_t stream) {
    const float* x = (const float*)d_in[0];
    float* out = (float*)d_out;

    // d_out doubles as scratch until the zero pass:
    //   [0, 134MB)   16-bit monotone dist keys [16][2048][2048]  (last read: topk)
    //   [134, 235MB) bf16 normalized features hi [16][2048][1536] (last read: gemm)
    unsigned short* dist = (unsigned short*)d_out;
    unsigned short* hi   = (unsigned short*)((char*)d_out + 134217728);

    // ws: invn 128KB | cand 1MB
    float* invn = (float*)d_ws;
    int*   cand = (int*)(invn + NROWS);

    normconv_kernel<<<NROWS / 4, 256, 0, stream>>>(x, invn, hi);
    gemm_kernel<<<NTRI * BB, 256, 0, stream>>>(hi, dist);
    topk_kernel<<<NROWS / 4, 256, 0, stream>>>(dist, cand);
    zero_kernel<<<OUTSZ / (256 * 32), 256, 0, stream>>>((float4*)out);   // 8192 blocks
    rescore_kernel<<<NROWS / 4, 256, 0, stream>>>(x, invn, cand, out);
}